// Round 16
// baseline (93.370 us; speedup 1.0000x reference)
//
#include <hip/hip_runtime.h>
#include <hip/hip_bf16.h>

#define ALPHA 0.2f
#define NROW 8192

typedef __attribute__((ext_vector_type(4))) float f4;
typedef __attribute__((ext_vector_type(8))) short s8;

__device__ __forceinline__ short f2bf_bits(float x){
    __hip_bfloat16 b = __float2bfloat16(x);
    return __builtin_bit_cast(short, b);
}

__device__ __forceinline__ void gload_lds16(const void* g, void* l){
    __builtin_amdgcn_global_load_lds(
        (const __attribute__((address_space(1))) void*)g,
        (__attribute__((address_space(3))) void*)l, 16, 0, 0);
}

// K1: h = x@W ; s1 ; F1=exp(s2) ; F2=exp(0.2*s2) ; hpack in MFMA B-fragment order.
__global__ __launch_bounds__(256) void k_proj(
    const float* __restrict__ x, const float* __restrict__ W, const float* __restrict__ a,
    float* __restrict__ s1,
    float* __restrict__ F1, float* __restrict__ F2, __hip_bfloat16* __restrict__ hpack)
{
    __shared__ float Wsh[128*64];   // 32 KB
    __shared__ float xsh[32*128];   // 16 KB
    const int t = threadIdx.x;
    const int f = t & 63, wq = t >> 6;
    const int row0 = blockIdx.x * 32;
    for (int i = t; i < 128*64; i += 256) Wsh[i] = W[i];
    for (int i = t; i < 32*128; i += 256) xsh[i] = x[row0*128 + i];
    __syncthreads();
    const float a1 = a[f], a2 = a[64 + f];
    #pragma unroll 1
    for (int rr = 0; rr < 8; ++rr){
        const int ry = wq*8 + rr;
        float acc = 0.f;
        #pragma unroll
        for (int k = 0; k < 128; ++k) acc = fmaf(xsh[ry*128 + k], Wsh[k*64 + f], acc);
        float p1 = acc * a1, p2 = acc * a2;
        #pragma unroll
        for (int m = 32; m; m >>= 1){ p1 += __shfl_xor(p1, m, 64); p2 += __shfl_xor(p2, m, 64); }
        const int j = row0 + ry;
        if (f == 0){
            s1[j] = p1;
            F1[j] = __expf(p2); F2[j] = __expf(0.2f * p2);
        }
        const int sc = j >> 5, hg = (j >> 3) & 3, e = j & 7;
        const int fg = f >> 4, lr = f & 15;
        hpack[(((sc*4 + fg)*64) + hg*16 + lr)*8 + e] = __float2bfloat16(acc);
    }
}

// K3: R12 inner loop verbatim; grid/LDS reshaped for 2 blocks/CU.
// block = (jslab: 1024 cols) x (igrp: 128 rows), 512 blocks, 512 threads.
// 4 sub-windows of 256 cols; h dbuf 2x32KB + F 8KB = 73728 B LDS.
// adj = only loop vm traffic, 8 slots, counted W14; raw s_barrier per window.
__global__ __launch_bounds__(512, 2) void k_gat(
    const float* __restrict__ adj, const float* __restrict__ s1g,
    const float* __restrict__ F1g, const float* __restrict__ F2g,
    const __hip_bfloat16* __restrict__ hpack,
    float* __restrict__ part, float* __restrict__ pden)
{
    __shared__ __attribute__((aligned(16))) char arena[73728]; // 2x32K h + 4K F1 + 4K F2

    const int tid = threadIdx.x;
    const int w = tid >> 6, lane = tid & 63;
    const int lr = lane & 15, hi = lane >> 4;
    const int jslab = blockIdx.x >> 6, igrp = blockIdx.x & 63;

    float* F1sl = (float*)(arena + 65536);
    float* F2sl = (float*)(arena + 69632);

    const int rbA = igrp*128 + w*16;
    const int row = rbA + lr;
    const float s1r = s1g[row];
    const float E1 = __expf(s1r), E2 = __expf(ALPHA*s1r), T1 = __expf(-s1r);

#define STAGEH(buf, sw_) do { \
    const s8* hp_ = (const s8*)hpack + (jslab*32 + (sw_)*8)*256 + w*256 + lane; \
    char* dst_ = arena + (buf)*32768 + w*4096; \
    _Pragma("unroll") \
    for (int it_ = 0; it_ < 4; ++it_) \
        gload_lds16(hp_ + it_*64, dst_ + it_*1024); \
} while(0)

    // prologue: h sub-window 0 -> buf0, F full slab (1024 cols)
    STAGEH(0, 0);
    *(float2*)&F1sl[tid*2] = *(const float2*)(F1g + jslab*1024 + tid*2);
    *(float2*)&F2sl[tid*2] = *(const float2*)(F2g + jslab*1024 + tid*2);

    // adj per-lane pointer: rows rbA + (lane>>3) (+8 for 2nd load), cols (lane&7)*4
    const float* padj = adj + (long)(rbA + (lane >> 3))*NROW + jslab*1024 + (lane & 7)*4;
    const unsigned bsh = (unsigned)((lr & 7)*8 + hi*2);
    const int hi8 = hi * 8;

    f4 acc0={0,0,0,0}, acc1={0,0,0,0}, acc2={0,0,0,0}, acc3={0,0,0,0};
    float lsum = 0.f;

    f4 v0S0,v1S0, v0S1,v1S1, v0S2,v1S2, v0S3,v1S3;
    f4 v0S4,v1S4, v0S5,v1S5, v0S6,v1S6, v0S7,v1S7;

#define LOAD(S, s_) do { \
    const int o_ = (s_) * 32; \
    v0##S = *(const f4*)(padj + o_); \
    v1##S = *(const f4*)(padj + o_ + 8*NROW); \
} while(0)

#define CALCQ(cond, g1, g2, qd) { \
    float fz = ((g1) > T1) ? (g1) * E1 : (g2) * E2; \
    qd = (cond) ? fz : 0.f; }

#define STEP(S, s_) do { \
    unsigned long long c0_ = __ballot(v0##S[0] > 0.f); \
    unsigned long long c1_ = __ballot(v0##S[1] > 0.f); \
    unsigned long long c2_ = __ballot(v0##S[2] > 0.f); \
    unsigned long long c3_ = __ballot(v0##S[3] > 0.f); \
    unsigned long long d0_ = __ballot(v1##S[0] > 0.f); \
    unsigned long long d1_ = __ballot(v1##S[1] > 0.f); \
    unsigned long long d2_ = __ballot(v1##S[2] > 0.f); \
    unsigned long long d3_ = __ballot(v1##S[3] > 0.f); \
    const unsigned u0 = (unsigned)(((lr < 8) ? c0_ : d0_) >> bsh); \
    const unsigned u1 = (unsigned)(((lr < 8) ? c1_ : d1_) >> bsh); \
    const unsigned u2 = (unsigned)(((lr < 8) ? c2_ : d2_) >> bsh); \
    const unsigned u3 = (unsigned)(((lr < 8) ? c3_ : d3_) >> bsh); \
    const s8* hb_ = (const s8*)(arena + (((s_) >> 3) & 1)*32768) + ((s_) & 7)*256; \
    s8 h0 = hb_[lane]; s8 h1 = hb_[64 + lane]; \
    s8 h2 = hb_[128 + lane]; s8 h3 = hb_[192 + lane]; \
    f4 f1a = *(const f4*)&F1sl[(s_)*32 + hi8]; f4 f1b = *(const f4*)&F1sl[(s_)*32 + hi8 + 4]; \
    f4 f2a = *(const f4*)&F2sl[(s_)*32 + hi8]; f4 f2b = *(const f4*)&F2sl[(s_)*32 + hi8 + 4]; \
    float q0,q1,q2,q3,q4,q5,q6,q7; \
    CALCQ(u0 & 1u, f1a[0], f2a[0], q0); CALCQ(u1 & 1u, f1a[1], f2a[1], q1); \
    CALCQ(u2 & 1u, f1a[2], f2a[2], q2); CALCQ(u3 & 1u, f1a[3], f2a[3], q3); \
    CALCQ(u0 & 2u, f1b[0], f2b[0], q4); CALCQ(u1 & 2u, f1b[1], f2b[1], q5); \
    CALCQ(u2 & 2u, f1b[2], f2b[2], q6); CALCQ(u3 & 2u, f1b[3], f2b[3], q7); \
    lsum += ((q0+q1)+(q2+q3)) + ((q4+q5)+(q6+q7)); \
    s8 af; \
    af[0]=f2bf_bits(q0); af[1]=f2bf_bits(q1); af[2]=f2bf_bits(q2); af[3]=f2bf_bits(q3); \
    af[4]=f2bf_bits(q4); af[5]=f2bf_bits(q5); af[6]=f2bf_bits(q6); af[7]=f2bf_bits(q7); \
    acc0 = __builtin_amdgcn_mfma_f32_16x16x32_bf16(af, h0, acc0, 0, 0, 0); \
    acc1 = __builtin_amdgcn_mfma_f32_16x16x32_bf16(af, h1, acc1, 0, 0, 0); \
    acc2 = __builtin_amdgcn_mfma_f32_16x16x32_bf16(af, h2, acc2, 0, 0, 0); \
    acc3 = __builtin_amdgcn_mfma_f32_16x16x32_bf16(af, h3, acc3, 0, 0, 0); \
} while(0)

#define W14 asm volatile("s_waitcnt vmcnt(14)" ::: "memory")

    LOAD(S0, 0); LOAD(S1, 1); LOAD(S2, 2); LOAD(S3, 3);
    LOAD(S4, 4); LOAD(S5, 5); LOAD(S6, 6); LOAD(S7, 7);
    __syncthreads();   // drains prologue staging + slot prefetch

    // windows 0..2 (steps 0..23): stage next h, 8 steps, raw barrier
    #pragma unroll 1
    for (int sw = 0; sw < 3; ++sw){
        const int st = sw * 8;
        STAGEH((sw + 1) & 1, sw + 1);      // retires under this window's W14s
        W14; STEP(S0, st    ); LOAD(S0, st + 8);
        W14; STEP(S1, st + 1); LOAD(S1, st + 9);
        W14; STEP(S2, st + 2); LOAD(S2, st + 10);
        W14; STEP(S3, st + 3); LOAD(S3, st + 11);
        W14; STEP(S4, st + 4); LOAD(S4, st + 12);
        W14; STEP(S5, st + 5); LOAD(S5, st + 13);
        W14; STEP(S6, st + 6); LOAD(S6, st + 14);
        W14; STEP(S7, st + 7); LOAD(S7, st + 15);
        asm volatile("s_barrier" ::: "memory");   // raw: no vmcnt drain
    }
    // window 3 (steps 24..31): drain ladder, no loads
    W14;                                              STEP(S0, 24);
    asm volatile("s_waitcnt vmcnt(12)" ::: "memory"); STEP(S1, 25);
    asm volatile("s_waitcnt vmcnt(10)" ::: "memory"); STEP(S2, 26);
    asm volatile("s_waitcnt vmcnt(8)"  ::: "memory"); STEP(S3, 27);
    asm volatile("s_waitcnt vmcnt(6)"  ::: "memory"); STEP(S4, 28);
    asm volatile("s_waitcnt vmcnt(4)"  ::: "memory"); STEP(S5, 29);
    asm volatile("s_waitcnt vmcnt(2)"  ::: "memory"); STEP(S6, 30);
    asm volatile("s_waitcnt vmcnt(0)"  ::: "memory"); STEP(S7, 31);

#undef LOAD
#undef CALCQ
#undef STEP
#undef W14
#undef STAGEH

    lsum += __shfl_xor(lsum, 16, 64);
    lsum += __shfl_xor(lsum, 32, 64);

    // partial stores (C layout: col = lr, row = hi*4 + r, col-block q*16)
    {
        const long pb = ((long)jslab*NROW + rbA + hi*4)*64 + lr;
        #pragma unroll
        for (int r = 0; r < 4; ++r){
            part[pb + r*64 +  0] = acc0[r];
            part[pb + r*64 + 16] = acc1[r];
            part[pb + r*64 + 32] = acc2[r];
            part[pb + r*64 + 48] = acc3[r];
        }
        if (lane < 16) pden[jslab*NROW + rbA + lr] = lsum;
    }
}

// K4: combine 8 jslab partials, divide, ELU, store out.
__global__ __launch_bounds__(256) void k_comb(
    const float* __restrict__ part, const float* __restrict__ pden,
    float* __restrict__ out)
{
    const int idx = blockIdx.x*256 + threadIdx.x;   // 8192*16
    const int i = idx >> 4, c4 = (idx & 15) << 2;
    f4 sa = {0.f,0.f,0.f,0.f}; float L = 0.f;
    #pragma unroll
    for (int s = 0; s < 8; ++s){
        sa += *(const f4*)&part[((long)s*NROW + i)*64 + c4];
        L  += pden[s*NROW + i];
    }
    const float inv = 1.f / L;
    f4 o;
    #pragma unroll
    for (int e = 0; e < 4; ++e){
        float v = sa[e] * inv;
        o[e] = (v > 0.f) ? v : expm1f(v);
    }
    *(f4*)&out[(long)i*64 + c4] = o;
}

extern "C" void kernel_launch(void* const* d_in, const int* in_sizes, int n_in,
                              void* d_out, int out_size, void* d_ws, size_t ws_size,
                              hipStream_t stream)
{
    const float* x   = (const float*)d_in[0];
    const float* adj = (const float*)d_in[1];
    const float* W   = (const float*)d_in[2];
    const float* a   = (const float*)d_in[3];
    float* out = (float*)d_out;

    char* ws = (char*)d_ws;
    float* s1   = (float*)(ws);                    // 32 KB
    float* F1   = (float*)(ws + 65536);            // 32 KB
    float* F2   = (float*)(ws + 98304);            // 32 KB
    __hip_bfloat16* hpack = (__hip_bfloat16*)(ws + 131328);   // 1 MB
    float* part = (float*)(ws + 1179904);          // 16 MB (8 x 8192 x 64)
    float* pden = (float*)(ws + 17957120);         // 256 KB (8 x 8192)

    k_proj <<<256, 256, 0, stream>>>(x, W, a, s1, F1, F2, hpack);
    k_gat  <<<512, 512, 0, stream>>>(adj, s1, F1, F2, hpack, part, pden);
    k_comb <<<512, 256, 0, stream>>>(part, pden, out);
}

// Round 18
// 67.667 us; speedup vs baseline: 1.3798x; 1.3798x over previous
//
#include <hip/hip_runtime.h>
#include <hip/hip_bf16.h>

#define ALPHA 0.2f
#define NROW 8192

typedef __attribute__((ext_vector_type(4))) float f4;
typedef __attribute__((ext_vector_type(8))) short s8;

__device__ __forceinline__ short f2bf_bits(float x){
    __hip_bfloat16 b = __float2bfloat16(x);
    return __builtin_bit_cast(short, b);
}

__device__ __forceinline__ void gload_lds16(const void* g, void* l){
    __builtin_amdgcn_global_load_lds(
        (const __attribute__((address_space(1))) void*)g,
        (__attribute__((address_space(3))) void*)l, 16, 0, 0);
}

// K1: h = x@W ; s1 ; F1=exp(s2) ; F2=exp(0.2*s2) ; hpack in MFMA B-fragment order.
__global__ __launch_bounds__(256) void k_proj(
    const float* __restrict__ x, const float* __restrict__ W, const float* __restrict__ a,
    float* __restrict__ s1,
    float* __restrict__ F1, float* __restrict__ F2, __hip_bfloat16* __restrict__ hpack)
{
    __shared__ float Wsh[128*64];   // 32 KB
    __shared__ float xsh[32*128];   // 16 KB
    const int t = threadIdx.x;
    const int f = t & 63, wq = t >> 6;
    const int row0 = blockIdx.x * 32;
    for (int i = t; i < 128*64; i += 256) Wsh[i] = W[i];
    for (int i = t; i < 32*128; i += 256) xsh[i] = x[row0*128 + i];
    __syncthreads();
    const float a1 = a[f], a2 = a[64 + f];
    #pragma unroll 1
    for (int rr = 0; rr < 8; ++rr){
        const int ry = wq*8 + rr;
        float acc = 0.f;
        #pragma unroll
        for (int k = 0; k < 128; ++k) acc = fmaf(xsh[ry*128 + k], Wsh[k*64 + f], acc);
        float p1 = acc * a1, p2 = acc * a2;
        #pragma unroll
        for (int m = 32; m; m >>= 1){ p1 += __shfl_xor(p1, m, 64); p2 += __shfl_xor(p2, m, 64); }
        const int j = row0 + ry;
        if (f == 0){
            s1[j] = p1;
            F1[j] = __expf(p2); F2[j] = __expf(0.2f * p2);
        }
        const int sc = j >> 5, hg = (j >> 3) & 3, e = j & 7;
        const int fg = f >> 4, lr = f & 15;
        hpack[(((sc*4 + fg)*64) + hg*16 + lr)*8 + e] = __float2bfloat16(acc);
    }
}

// K3 (R12-proven, final): block = (jslab: 2048 cols) x (igrp: 128 rows).
// 4 sub-windows of 512 cols; h double-buffered 2x64KB (staged at window start,
// retires under the window's W14s); raw s_barrier per sub-window (no vmcnt
// drain -> adj pipeline unbroken across all 64 steps). F staged upfront.
// adj = the ONLY in-loop vm traffic (h/F on lgkmcnt), 8 reg slots, counted W14.
__global__ __launch_bounds__(512, 2) void k_gat(
    const float* __restrict__ adj, const float* __restrict__ s1g,
    const float* __restrict__ F1g, const float* __restrict__ F2g,
    const __hip_bfloat16* __restrict__ hpack,
    float* __restrict__ part, float* __restrict__ pden)
{
    __shared__ __attribute__((aligned(16))) char arena[147456]; // 2x64K h + 8K F1 + 8K F2

    const int tid = threadIdx.x;
    const int w = tid >> 6, lane = tid & 63;
    const int lr = lane & 15, hi = lane >> 4;
    const int jslab = blockIdx.x >> 6, igrp = blockIdx.x & 63;

    float* F1sl = (float*)(arena + 131072);
    float* F2sl = (float*)(arena + 139264);

    const int rbA = igrp*128 + w*16;
    const int row = rbA + lr;
    const float s1r = s1g[row];
    const float E1 = __expf(s1r), E2 = __expf(ALPHA*s1r), T1 = __expf(-s1r);

#define STAGEH(buf, sw_) do { \
    const s8* hp_ = (const s8*)hpack + (jslab*64 + (sw_)*16)*256 + w*512 + lane; \
    char* dst_ = arena + (buf)*65536 + (w*512)*16; \
    _Pragma("unroll") \
    for (int it_ = 0; it_ < 8; ++it_) \
        gload_lds16(hp_ + it_*64, dst_ + it_*1024); \
} while(0)

    // prologue: h sub-window 0 -> buf0, F full slab
    STAGEH(0, 0);
    *(f4*)&F1sl[tid*4] = *(const f4*)(F1g + jslab*2048 + tid*4);
    *(f4*)&F2sl[tid*4] = *(const f4*)(F2g + jslab*2048 + tid*4);
    __syncthreads();   // drains prologue staging

    // adj per-lane pointer: rows rbA + (lane>>3) (+8 for 2nd load), cols (lane&7)*4
    const float* padj = adj + (long)(rbA + (lane >> 3))*NROW + jslab*2048 + (lane & 7)*4;
    const unsigned bsh = (unsigned)((lr & 7)*8 + hi*2);
    const int hi8 = hi * 8;

    f4 acc0={0,0,0,0}, acc1={0,0,0,0}, acc2={0,0,0,0}, acc3={0,0,0,0};
    float lsum = 0.f;

    f4 v0S0,v1S0, v0S1,v1S1, v0S2,v1S2, v0S3,v1S3;
    f4 v0S4,v1S4, v0S5,v1S5, v0S6,v1S6, v0S7,v1S7;

#define LOAD(S, s_) do { \
    const int o_ = (s_) * 32; \
    v0##S = *(const f4*)(padj + o_); \
    v1##S = *(const f4*)(padj + o_ + 8*NROW); \
} while(0)

#define CALCQ(cond, g1, g2, qd) { \
    float fz = ((g1) > T1) ? (g1) * E1 : (g2) * E2; \
    qd = (cond) ? fz : 0.f; }

#define STEP(S, s_) do { \
    unsigned long long c0_ = __ballot(v0##S[0] > 0.f); \
    unsigned long long c1_ = __ballot(v0##S[1] > 0.f); \
    unsigned long long c2_ = __ballot(v0##S[2] > 0.f); \
    unsigned long long c3_ = __ballot(v0##S[3] > 0.f); \
    unsigned long long d0_ = __ballot(v1##S[0] > 0.f); \
    unsigned long long d1_ = __ballot(v1##S[1] > 0.f); \
    unsigned long long d2_ = __ballot(v1##S[2] > 0.f); \
    unsigned long long d3_ = __ballot(v1##S[3] > 0.f); \
    const unsigned u0 = (unsigned)(((lr < 8) ? c0_ : d0_) >> bsh); \
    const unsigned u1 = (unsigned)(((lr < 8) ? c1_ : d1_) >> bsh); \
    const unsigned u2 = (unsigned)(((lr < 8) ? c2_ : d2_) >> bsh); \
    const unsigned u3 = (unsigned)(((lr < 8) ? c3_ : d3_) >> bsh); \
    const s8* hb_ = (const s8*)(arena + (((s_) >> 4) & 1)*65536) + ((s_) & 15)*256; \
    s8 h0 = hb_[lane]; s8 h1 = hb_[64 + lane]; \
    s8 h2 = hb_[128 + lane]; s8 h3 = hb_[192 + lane]; \
    f4 f1a = *(const f4*)&F1sl[(s_)*32 + hi8]; f4 f1b = *(const f4*)&F1sl[(s_)*32 + hi8 + 4]; \
    f4 f2a = *(const f4*)&F2sl[(s_)*32 + hi8]; f4 f2b = *(const f4*)&F2sl[(s_)*32 + hi8 + 4]; \
    float q0,q1,q2,q3,q4,q5,q6,q7; \
    CALCQ(u0 & 1u, f1a[0], f2a[0], q0); CALCQ(u1 & 1u, f1a[1], f2a[1], q1); \
    CALCQ(u2 & 1u, f1a[2], f2a[2], q2); CALCQ(u3 & 1u, f1a[3], f2a[3], q3); \
    CALCQ(u0 & 2u, f1b[0], f2b[0], q4); CALCQ(u1 & 2u, f1b[1], f2b[1], q5); \
    CALCQ(u2 & 2u, f1b[2], f2b[2], q6); CALCQ(u3 & 2u, f1b[3], f2b[3], q7); \
    lsum += ((q0+q1)+(q2+q3)) + ((q4+q5)+(q6+q7)); \
    s8 af; \
    af[0]=f2bf_bits(q0); af[1]=f2bf_bits(q1); af[2]=f2bf_bits(q2); af[3]=f2bf_bits(q3); \
    af[4]=f2bf_bits(q4); af[5]=f2bf_bits(q5); af[6]=f2bf_bits(q6); af[7]=f2bf_bits(q7); \
    acc0 = __builtin_amdgcn_mfma_f32_16x16x32_bf16(af, h0, acc0, 0, 0, 0); \
    acc1 = __builtin_amdgcn_mfma_f32_16x16x32_bf16(af, h1, acc1, 0, 0, 0); \
    acc2 = __builtin_amdgcn_mfma_f32_16x16x32_bf16(af, h2, acc2, 0, 0, 0); \
    acc3 = __builtin_amdgcn_mfma_f32_16x16x32_bf16(af, h3, acc3, 0, 0, 0); \
} while(0)

#define W14 asm volatile("s_waitcnt vmcnt(14)" ::: "memory")
#define ROUND8(stb) do { \
    W14; STEP(S0, (stb)    ); LOAD(S0, (stb) + 8); \
    W14; STEP(S1, (stb) + 1); LOAD(S1, (stb) + 9); \
    W14; STEP(S2, (stb) + 2); LOAD(S2, (stb) + 10); \
    W14; STEP(S3, (stb) + 3); LOAD(S3, (stb) + 11); \
    W14; STEP(S4, (stb) + 4); LOAD(S4, (stb) + 12); \
    W14; STEP(S5, (stb) + 5); LOAD(S5, (stb) + 13); \
    W14; STEP(S6, (stb) + 6); LOAD(S6, (stb) + 14); \
    W14; STEP(S7, (stb) + 7); LOAD(S7, (stb) + 15); \
} while(0)

    LOAD(S0, 0); LOAD(S1, 1); LOAD(S2, 2); LOAD(S3, 3);
    LOAD(S4, 4); LOAD(S5, 5); LOAD(S6, 6); LOAD(S7, 7);

    #pragma unroll 1
    for (int sw = 0; sw < 3; ++sw){
        STAGEH((sw + 1) & 1, sw + 1);      // next sub-window's h; retires under W14s
        const int stb = sw * 16;
        ROUND8(stb); ROUND8(stb + 8);
        asm volatile("s_barrier" ::: "memory");   // raw: no vmcnt drain
    }
    ROUND8(48);
    // tail: steps 56..63, drain
    W14;                                              STEP(S0, 56);
    asm volatile("s_waitcnt vmcnt(12)" ::: "memory"); STEP(S1, 57);
    asm volatile("s_waitcnt vmcnt(10)" ::: "memory"); STEP(S2, 58);
    asm volatile("s_waitcnt vmcnt(8)"  ::: "memory"); STEP(S3, 59);
    asm volatile("s_waitcnt vmcnt(6)"  ::: "memory"); STEP(S4, 60);
    asm volatile("s_waitcnt vmcnt(4)"  ::: "memory"); STEP(S5, 61);
    asm volatile("s_waitcnt vmcnt(2)"  ::: "memory"); STEP(S6, 62);
    asm volatile("s_waitcnt vmcnt(0)"  ::: "memory"); STEP(S7, 63);

#undef LOAD
#undef CALCQ
#undef STEP
#undef W14
#undef ROUND8
#undef STAGEH

    lsum += __shfl_xor(lsum, 16, 64);
    lsum += __shfl_xor(lsum, 32, 64);

    // partial stores (C layout: col = lr, row = hi*4 + r, col-block q*16)
    {
        const long pb = ((long)jslab*NROW + rbA + hi*4)*64 + lr;
        #pragma unroll
        for (int r = 0; r < 4; ++r){
            part[pb + r*64 +  0] = acc0[r];
            part[pb + r*64 + 16] = acc1[r];
            part[pb + r*64 + 32] = acc2[r];
            part[pb + r*64 + 48] = acc3[r];
        }
        if (lane < 16) pden[jslab*NROW + rbA + lr] = lsum;
    }
}

// K4: combine 4 jslab partials, divide, ELU, store out.
__global__ __launch_bounds__(256) void k_comb(
    const float* __restrict__ part, const float* __restrict__ pden,
    float* __restrict__ out)
{
    const int idx = blockIdx.x*256 + threadIdx.x;   // 8192*16
    const int i = idx >> 4, c4 = (idx & 15) << 2;
    f4 sa = {0.f,0.f,0.f,0.f}; float L = 0.f;
    #pragma unroll
    for (int s = 0; s < 4; ++s){
        sa += *(const f4*)&part[((long)s*NROW + i)*64 + c4];
        L  += pden[s*NROW + i];
    }
    const float inv = 1.f / L;
    f4 o;
    #pragma unroll
    for (int e = 0; e < 4; ++e){
        float v = sa[e] * inv;
        o[e] = (v > 0.f) ? v : expm1f(v);
    }
    *(f4*)&out[(long)i*64 + c4] = o;
}

extern "C" void kernel_launch(void* const* d_in, const int* in_sizes, int n_in,
                              void* d_out, int out_size, void* d_ws, size_t ws_size,
                              hipStream_t stream)
{
    const float* x   = (const float*)d_in[0];
    const float* adj = (const float*)d_in[1];
    const float* W   = (const float*)d_in[2];
    const float* a   = (const float*)d_in[3];
    float* out = (float*)d_out;

    char* ws = (char*)d_ws;
    float* s1   = (float*)(ws);                    // 32 KB
    float* F1   = (float*)(ws + 65536);            // 32 KB
    float* F2   = (float*)(ws + 98304);            // 32 KB
    __hip_bfloat16* hpack = (__hip_bfloat16*)(ws + 131328);   // 1 MB
    float* part = (float*)(ws + 1179904);          // 8 MB (4 x 8192 x 64)
    float* pden = (float*)(ws + 9568512);          // 128 KB (4 x 8192)

    k_proj <<<256, 256, 0, stream>>>(x, W, a, s1, F1, F2, hpack);
    k_gat  <<<256, 512, 0, stream>>>(adj, s1, F1, F2, hpack, part, pden);
    k_comb <<<512, 256, 0, stream>>>(part, pden, out);
}